// Round 1
// baseline (195.719 us; speedup 1.0000x reference)
//
#include <hip/hip_runtime.h>

typedef __bf16 bf16_t;
typedef __bf16 bf16x8 __attribute__((ext_vector_type(8)));
typedef __bf16 bf16x4 __attribute__((ext_vector_type(4)));
typedef float  f32x4  __attribute__((ext_vector_type(4)));

#define B_DIM 4
#define S_DIM 4096
#define D_DIM 1024
#define M_DIM (B_DIM * S_DIM)   // 16384 rows

#define CHUNK 64   // output steps per scan block
#define WARM  24   // warm-up steps (contraction ~0.28^24 < 1e-13 worst case)

__device__ __forceinline__ void g2l16(const void* g, void* l) {
  __builtin_amdgcn_global_load_lds(
      (const __attribute__((address_space(1))) void*)g,
      (__attribute__((address_space(3))) void*)l, 16, 0, 0);
}

// ---------------- LayerNorm fp32 -> bf16, one wave per row ----------------
__global__ __launch_bounds__(64) void ln_kernel(
    const float* __restrict__ x, const float* __restrict__ gamma,
    const float* __restrict__ beta, bf16_t* __restrict__ h) {
  const int row  = blockIdx.x;
  const int lane = threadIdx.x;
  const float4* xr = (const float4*)(x + (size_t)row * D_DIM);
  float4 v[4];
  float s = 0.f, s2 = 0.f;
#pragma unroll
  for (int j = 0; j < 4; ++j) {
    v[j] = xr[j * 64 + lane];
    s += v[j].x + v[j].y + v[j].z + v[j].w;
    s2 = fmaf(v[j].x, v[j].x, s2);
    s2 = fmaf(v[j].y, v[j].y, s2);
    s2 = fmaf(v[j].z, v[j].z, s2);
    s2 = fmaf(v[j].w, v[j].w, s2);
  }
#pragma unroll
  for (int off = 32; off; off >>= 1) {
    s  += __shfl_xor(s, off);
    s2 += __shfl_xor(s2, off);
  }
  const float mu  = s * (1.f / (float)D_DIM);
  const float var = fmaf(-mu, mu, s2 * (1.f / (float)D_DIM));
  const float inv = rsqrtf(var + 1e-5f);
  bf16_t* hr = h + (size_t)row * D_DIM;
#pragma unroll
  for (int j = 0; j < 4; ++j) {
    const float4 g4 = ((const float4*)gamma)[j * 64 + lane];
    const float4 b4 = ((const float4*)beta)[j * 64 + lane];
    bf16x4 o;
    o[0] = (bf16_t)fmaf((v[j].x - mu) * inv, g4.x, b4.x);
    o[1] = (bf16_t)fmaf((v[j].y - mu) * inv, g4.y, b4.y);
    o[2] = (bf16_t)fmaf((v[j].z - mu) * inv, g4.z, b4.z);
    o[3] = (bf16_t)fmaf((v[j].w - mu) * inv, g4.w, b4.w);
    ((bf16x4*)hr)[j * 64 + lane] = o;
  }
}

// ------------- W [K][N] fp32  ->  WT [N][K] bf16 (tiled transpose) --------
__global__ __launch_bounds__(256) void transpose_kernel(
    const float* __restrict__ W, bf16_t* __restrict__ WT) {
  __shared__ float tile[32][33];
  const int tx = threadIdx.x & 31;
  const int ty = threadIdx.x >> 5;  // 0..7
  const int bn = blockIdx.x * 32;   // n base
  const int bk = blockIdx.y * 32;   // k base
#pragma unroll
  for (int i = 0; i < 32; i += 8)
    tile[ty + i][tx] = W[(size_t)(bk + ty + i) * D_DIM + bn + tx];
  __syncthreads();
#pragma unroll
  for (int i = 0; i < 32; i += 8)
    WT[(size_t)(bn + ty + i) * D_DIM + bk + tx] = (bf16_t)tile[tx][ty + i];
}

// ---------------- bf16 NT GEMM: C[M][N] = A[M][K] * BT[N][K]^T ------------
// MODE 0: Cout = bf16(acc + bias)          (produces c for the scan)
// MODE 1: Cout = f32 (acc + bias + xres)   (final output w/ residual)
template <int MODE>
__global__ __launch_bounds__(256) void gemm_nt_kernel(
    const bf16_t* __restrict__ A, const bf16_t* __restrict__ BT,
    const float* __restrict__ bias, const float* __restrict__ xres,
    void* __restrict__ Cout) {
  constexpr int K = D_DIM;
  constexpr int N = D_DIM;
  __shared__ __attribute__((aligned(16))) bf16_t As[128 * 32];
  __shared__ __attribute__((aligned(16))) bf16_t Bs[128 * 32];
  const int tid  = threadIdx.x;
  const int lane = tid & 63;
  const int wave = tid >> 6;
  const int wr = wave >> 1, wc = wave & 1;
  const int m0 = blockIdx.y * 128, n0 = blockIdx.x * 128;

  f32x4 acc[4][4];
#pragma unroll
  for (int m = 0; m < 4; ++m)
#pragma unroll
    for (int n = 0; n < 4; ++n) acc[m][n] = (f32x4){0.f, 0.f, 0.f, 0.f};

  // fragment read bases: lane holds row (lane&15), k-elems (lane>>4)*8..+7
  const char* aF = (const char*)As + (wr * 64 + (lane & 15)) * 64 + (lane >> 4) * 16;
  const char* bF = (const char*)Bs + (wc * 64 + (lane & 15)) * 64 + (lane >> 4) * 16;

  for (int k0 = 0; k0 < K; k0 += 32) {
    __syncthreads();  // previous iteration's ds_reads done before overwrite
#pragma unroll
    for (int i = 0; i < 2; ++i) {
      const int off = (i * 256 + tid) * 16;  // byte offset in 8KB tile (linear)
      const int row = off >> 6;              // 64 B per row (32 bf16)
      const int ke  = (off & 63) >> 1;       // k-element offset
      g2l16(A  + (size_t)(m0 + row) * K + k0 + ke, (char*)As + off);
      g2l16(BT + (size_t)(n0 + row) * K + k0 + ke, (char*)Bs + off);
    }
    __syncthreads();  // drains vmcnt -> staging visible
    bf16x8 a[4], b[4];
#pragma unroll
    for (int m = 0; m < 4; ++m) a[m] = *(const bf16x8*)(aF + m * 1024);
#pragma unroll
    for (int n = 0; n < 4; ++n) b[n] = *(const bf16x8*)(bF + n * 1024);
#pragma unroll
    for (int m = 0; m < 4; ++m)
#pragma unroll
      for (int n = 0; n < 4; ++n)
        acc[m][n] =
            __builtin_amdgcn_mfma_f32_16x16x32_bf16(a[m], b[n], acc[m][n], 0, 0, 0);
  }

  // epilogue: C/D layout col = lane&15, row = (lane>>4)*4 + r
  const int rbase = m0 + wr * 64 + ((lane >> 4) << 2);
  const int cbase = n0 + wc * 64 + (lane & 15);
#pragma unroll
  for (int n = 0; n < 4; ++n) {
    const int col = cbase + n * 16;
    const float bn = bias[col];
#pragma unroll
    for (int m = 0; m < 4; ++m) {
      const int row = rbase + m * 16;
#pragma unroll
      for (int r = 0; r < 4; ++r) {
        const size_t idx = (size_t)(row + r) * N + col;
        if (MODE == 0)
          ((bf16_t*)Cout)[idx] = (bf16_t)(acc[m][n][r] + bn);
        else
          ((float*)Cout)[idx] = xres[idx] + acc[m][n][r] + bn;
      }
    }
  }
}

// ---------------- chunked chaotic scan, one wave per (batch, chunk) -------
// state: 512 complex pairs; lane holds pairs lane*8..lane*8+7
// re index d = lane*8+j, im index d = 512 + lane*8+j
__global__ __launch_bounds__(64) void scan_kernel(
    const bf16_t* __restrict__ c, bf16_t* __restrict__ y) {
  const int b     = blockIdx.y;
  const int chunk = blockIdx.x;
  const int t0    = chunk * CHUNK;
  const int start = (chunk == 0) ? 0 : t0 - WARM;  // z=0 at start; contraction
  const int tend  = t0 + CHUNK;                    // makes warm-up exact enough
  const int lane  = threadIdx.x;

  float zre[8], zim[8];
#pragma unroll
  for (int j = 0; j < 8; ++j) { zre[j] = 0.f; zim[j] = 0.f; }

  const bf16_t* crow = c + ((size_t)b * S_DIM + start) * D_DIM;
  bf16x8 cr = ((const bf16x8*)crow)[lane];
  bf16x8 ci = ((const bf16x8*)(crow + 512))[lane];

  for (int t = start; t < tend; ++t) {
    bf16x8 crn = cr, cin = ci;   // depth-1 prefetch of next step's c
    if (t + 1 < tend) {
      const bf16_t* nrow = c + ((size_t)b * S_DIM + (t + 1)) * D_DIM;
      crn = ((const bf16x8*)nrow)[lane];
      cin = ((const bf16x8*)(nrow + 512))[lane];
    }
    float nr[8], ni[8];
    float ss = 0.f;
#pragma unroll
    for (int j = 0; j < 8; ++j) {
      const float a  = zre[j], bb = zim[j];
      const float rr = fmaf(a, a, fmaf(-bb, bb, (float)cr[j]));  // re^2-im^2+c
      const float ii = fmaf(2.f * a, bb, (float)ci[j]);          // 2*re*im+c
      nr[j] = rr; ni[j] = ii;
      ss = fmaf(rr, rr, ss);
      ss = fmaf(ii, ii, ss);
    }
#pragma unroll
    for (int off = 32; off; off >>= 1) ss += __shfl_xor(ss, off);
    const float nrm = sqrtf(ss + 1e-12f);
    const float sc  = 2.0f / fmaxf(nrm, 2.0f);
#pragma unroll
    for (int j = 0; j < 8; ++j) { zre[j] = nr[j] * sc; zim[j] = ni[j] * sc; }
    if (t >= t0) {
      bf16_t* yrow = y + ((size_t)b * S_DIM + t) * D_DIM;
      bf16x8 yr, yi;
#pragma unroll
      for (int j = 0; j < 8; ++j) { yr[j] = (bf16_t)zre[j]; yi[j] = (bf16_t)zim[j]; }
      ((bf16x8*)yrow)[lane]       = yr;
      ((bf16x8*)(yrow + 512))[lane] = yi;
    }
    cr = crn; ci = cin;
  }
}

extern "C" void kernel_launch(void* const* d_in, const int* in_sizes, int n_in,
                              void* d_out, int out_size, void* d_ws, size_t ws_size,
                              hipStream_t stream) {
  const float* x     = (const float*)d_in[0];
  const float* gamma = (const float*)d_in[1];
  const float* beta  = (const float*)d_in[2];
  const float* W_in  = (const float*)d_in[3];
  const float* b_in  = (const float*)d_in[4];
  const float* W_out = (const float*)d_in[5];
  const float* b_out = (const float*)d_in[6];
  float* out = (float*)d_out;

  char* ws = (char*)d_ws;
  bf16_t* hy  = (bf16_t*)(ws);                  // 32 MiB: h, later reused for y
  bf16_t* cbf = (bf16_t*)(ws + (32ull << 20));  // 32 MiB: c (bf16)
  bf16_t* wti = (bf16_t*)(ws + (64ull << 20));  // 2 MiB:  W_in^T bf16
  bf16_t* wto = (bf16_t*)(ws + (66ull << 20));  // 2 MiB:  W_out^T bf16

  transpose_kernel<<<dim3(32, 32), 256, 0, stream>>>(W_in, wti);
  transpose_kernel<<<dim3(32, 32), 256, 0, stream>>>(W_out, wto);
  ln_kernel<<<M_DIM, 64, 0, stream>>>(x, gamma, beta, hy);
  gemm_nt_kernel<0><<<dim3(D_DIM / 128, M_DIM / 128), 256, 0, stream>>>(
      hy, wti, b_in, nullptr, cbf);
  scan_kernel<<<dim3(S_DIM / CHUNK, B_DIM), 64, 0, stream>>>(cbf, hy);
  gemm_nt_kernel<1><<<dim3(D_DIM / 128, M_DIM / 128), 256, 0, stream>>>(
      hy, wto, b_out, x, out);
}

// Round 2
// 179.528 us; speedup vs baseline: 1.0902x; 1.0902x over previous
//
#include <hip/hip_runtime.h>

typedef __bf16 bf16_t;
typedef __bf16 bf16x8 __attribute__((ext_vector_type(8)));
typedef __bf16 bf16x4 __attribute__((ext_vector_type(4)));
typedef float  f32x4  __attribute__((ext_vector_type(4)));

#define B_DIM 4
#define S_DIM 4096
#define D_DIM 1024
#define M_DIM (B_DIM * S_DIM)   // 16384 rows

#define CHUNK 64   // scan output steps per block
#define WARM  24   // scan warm-up steps

__device__ __forceinline__ void g2l16(const void* g, void* l) {
  __builtin_amdgcn_global_load_lds(
      (const __attribute__((address_space(1))) void*)g,
      (__attribute__((address_space(3))) void*)l, 16, 0, 0);
}

// ---------------- LayerNorm fp32 -> bf16, one wave per row ----------------
__global__ __launch_bounds__(64) void ln_kernel(
    const float* __restrict__ x, const float* __restrict__ gamma,
    const float* __restrict__ beta, bf16_t* __restrict__ h) {
  const int row  = blockIdx.x;
  const int lane = threadIdx.x;
  const float4* xr = (const float4*)(x + (size_t)row * D_DIM);
  float4 v[4];
  float s = 0.f, s2 = 0.f;
#pragma unroll
  for (int j = 0; j < 4; ++j) {
    v[j] = xr[j * 64 + lane];
    s += v[j].x + v[j].y + v[j].z + v[j].w;
    s2 = fmaf(v[j].x, v[j].x, s2);
    s2 = fmaf(v[j].y, v[j].y, s2);
    s2 = fmaf(v[j].z, v[j].z, s2);
    s2 = fmaf(v[j].w, v[j].w, s2);
  }
#pragma unroll
  for (int off = 32; off; off >>= 1) {
    s  += __shfl_xor(s, off);
    s2 += __shfl_xor(s2, off);
  }
  const float mu  = s * (1.f / (float)D_DIM);
  const float var = fmaf(-mu, mu, s2 * (1.f / (float)D_DIM));
  const float inv = rsqrtf(var + 1e-5f);
  bf16_t* hr = h + (size_t)row * D_DIM;
#pragma unroll
  for (int j = 0; j < 4; ++j) {
    const float4 g4 = ((const float4*)gamma)[j * 64 + lane];
    const float4 b4 = ((const float4*)beta)[j * 64 + lane];
    bf16x4 o;
    o[0] = (bf16_t)fmaf((v[j].x - mu) * inv, g4.x, b4.x);
    o[1] = (bf16_t)fmaf((v[j].y - mu) * inv, g4.y, b4.y);
    o[2] = (bf16_t)fmaf((v[j].z - mu) * inv, g4.z, b4.z);
    o[3] = (bf16_t)fmaf((v[j].w - mu) * inv, g4.w, b4.w);
    ((bf16x4*)hr)[j * 64 + lane] = o;
  }
}

// ------------- W [K][N] fp32  ->  WT [N][K] bf16 (tiled transpose) --------
__global__ __launch_bounds__(256) void transpose_kernel(
    const float* __restrict__ W, bf16_t* __restrict__ WT) {
  __shared__ float tile[32][33];
  const int tx = threadIdx.x & 31;
  const int ty = threadIdx.x >> 5;
  const int bn = blockIdx.x * 32;
  const int bk = blockIdx.y * 32;
#pragma unroll
  for (int i = 0; i < 32; i += 8)
    tile[ty + i][tx] = W[(size_t)(bk + ty + i) * D_DIM + bn + tx];
  __syncthreads();
#pragma unroll
  for (int i = 0; i < 32; i += 8)
    WT[(size_t)(bn + ty + i) * D_DIM + bk + tx] = (bf16_t)tile[tx][ty + i];
}

// ---------------- bf16 NT GEMM, 256x256 tile, 4-deep LDS ring -------------
// C[M][N] = A[M][K] * BT[N][K]^T ; MODE 0: bf16(acc+bias); MODE 1: f32 +x
#define BK 32
#define NT (D_DIM / BK)   // 32 K-tiles

#define VMCNT(n) asm volatile("s_waitcnt vmcnt(" #n ")" ::: "memory")

template <int MODE>
__global__ __launch_bounds__(512, 2) void gemm_nt_kernel(
    const bf16_t* __restrict__ A, const bf16_t* __restrict__ BT,
    const float* __restrict__ bias, const float* __restrict__ xres,
    void* __restrict__ Cout) {
  // ring of 4 K-tile buffers; each: A 16KB (256 rows x 64B) | B 16KB
  __shared__ __attribute__((aligned(16))) char lds[4][32768];
  const int tid  = threadIdx.x;
  const int lane = tid & 63;
  const int wave = tid >> 6;           // 0..7
  const int wr = wave >> 2;            // 0..1 (M half)
  const int wc = wave & 3;             // 0..3 (N quarter)
  // XCD-aware swizzle: 256 blocks, 8 XCDs, 32 contiguous per XCD
  const int bid = blockIdx.x;
  const int swz = (bid & 7) * 32 + (bid >> 3);
  const int m0 = (swz >> 2) * 256;     // 64 m-panels
  const int n0 = (swz & 3) * 256;      // 4  n-panels

  // --- staging source addresses (inverse-swizzled k-slot per lane) ---
  // LDS image: row*64B + slot*16B holds k-elems (slot ^ ((row>>1)&3))*8..+7
  const int ke  = ((tid & 3) ^ ((tid >> 3) & 3)) << 3;  // element offset
  const int r0_ = tid >> 2;                              // rows 0..127
  const bf16_t* sa0 = A  + (size_t)(m0 + r0_) * D_DIM + ke;
  const bf16_t* sa1 = A  + (size_t)(m0 + 128 + r0_) * D_DIM + ke;
  const bf16_t* sb0 = BT + (size_t)(n0 + r0_) * D_DIM + ke;
  const bf16_t* sb1 = BT + (size_t)(n0 + 128 + r0_) * D_DIM + ke;
  const int l16 = tid * 16;

  // --- fragment read offsets (swizzled) ---
  const int fx   = (((lane >> 4) ^ ((lane >> 1) & 3)) << 4);
  const int aoff = (wr * 128 + (lane & 15)) * 64 + fx;
  const int boff = 16384 + (wc * 64 + (lane & 15)) * 64 + fx;

  f32x4 acc[8][4];
#pragma unroll
  for (int m = 0; m < 8; ++m)
#pragma unroll
    for (int n = 0; n < 4; ++n) acc[m][n] = (f32x4){0.f, 0.f, 0.f, 0.f};

#define STAGE(KT)                                   \
  {                                                 \
    char* dst = lds[(KT) & 3];                      \
    const size_t ko = (size_t)(KT) * BK;            \
    g2l16(sa0 + ko, dst + l16);                     \
    g2l16(sa1 + ko, dst + 8192 + l16);              \
    g2l16(sb0 + ko, dst + 16384 + l16);             \
    g2l16(sb1 + ko, dst + 24576 + l16);             \
  }

#define GEMM_BODY(T)                                                         \
  {                                                                          \
    const char* bufp = lds[(T) & 3];                                         \
    bf16x8 af[8], bfr[4];                                                    \
    _Pragma("unroll") for (int m = 0; m < 8; ++m)                            \
        af[m] = *(const bf16x8*)(bufp + aoff + m * 1024);                    \
    _Pragma("unroll") for (int n = 0; n < 4; ++n)                            \
        bfr[n] = *(const bf16x8*)(bufp + boff + n * 1024);                   \
    __builtin_amdgcn_s_setprio(1);                                           \
    _Pragma("unroll") for (int m = 0; m < 8; ++m)                            \
        _Pragma("unroll") for (int n = 0; n < 4; ++n)                        \
            acc[m][n] = __builtin_amdgcn_mfma_f32_16x16x32_bf16(             \
                af[m], bfr[n], acc[m][n], 0, 0, 0);                          \
    __builtin_amdgcn_s_setprio(0);                                           \
    __builtin_amdgcn_s_barrier();                                            \
    asm volatile("" ::: "memory");                                           \
  }

  // prologue: tiles 0..2 in flight; retire tile 0, sync
  STAGE(0); STAGE(1); STAGE(2);
  VMCNT(8);
  __builtin_amdgcn_s_barrier();
  asm volatile("" ::: "memory");

  // steady state: stage t+3, retire t+1 (counted, never 0), compute t
  for (int t = 0; t < NT - 3; ++t) {
    STAGE(t + 3);
    VMCNT(8);
    GEMM_BODY(t);
  }
  VMCNT(4); GEMM_BODY(NT - 3);
  VMCNT(0); GEMM_BODY(NT - 2);
  GEMM_BODY(NT - 1);

#undef STAGE
#undef GEMM_BODY

  // epilogue: C/D layout col = lane&15, row = (lane>>4)*4 + r
  const int rbase = m0 + wr * 128 + ((lane >> 4) << 2);
  const int cbase = n0 + wc * 64 + (lane & 15);
#pragma unroll
  for (int n = 0; n < 4; ++n) {
    const int col = cbase + n * 16;
    const float bn = bias[col];
#pragma unroll
    for (int m = 0; m < 8; ++m) {
      const int row = rbase + m * 16;
#pragma unroll
      for (int r = 0; r < 4; ++r) {
        const size_t idx = (size_t)(row + r) * D_DIM + col;
        if (MODE == 0)
          ((bf16_t*)Cout)[idx] = (bf16_t)(acc[m][n][r] + bn);
        else
          ((float*)Cout)[idx] = xres[idx] + acc[m][n][r] + bn;
      }
    }
  }
}

// ---------------- chunked chaotic scan, one wave per (batch, chunk) -------
__global__ __launch_bounds__(64) void scan_kernel(
    const bf16_t* __restrict__ c, bf16_t* __restrict__ y) {
  const int b     = blockIdx.y;
  const int chunk = blockIdx.x;
  const int t0    = chunk * CHUNK;
  const int start = (chunk == 0) ? 0 : t0 - WARM;
  const int tend  = t0 + CHUNK;
  const int lane  = threadIdx.x;

  float zre[8], zim[8];
#pragma unroll
  for (int j = 0; j < 8; ++j) { zre[j] = 0.f; zim[j] = 0.f; }

  const bf16_t* crow = c + ((size_t)b * S_DIM + start) * D_DIM;
  bf16x8 cr = ((const bf16x8*)crow)[lane];
  bf16x8 ci = ((const bf16x8*)(crow + 512))[lane];

  for (int t = start; t < tend; ++t) {
    bf16x8 crn = cr, cin = ci;
    if (t + 1 < tend) {
      const bf16_t* nrow = c + ((size_t)b * S_DIM + (t + 1)) * D_DIM;
      crn = ((const bf16x8*)nrow)[lane];
      cin = ((const bf16x8*)(nrow + 512))[lane];
    }
    float nr[8], ni[8];
    float ss = 0.f;
#pragma unroll
    for (int j = 0; j < 8; ++j) {
      const float a  = zre[j], bb = zim[j];
      const float rr = fmaf(a, a, fmaf(-bb, bb, (float)cr[j]));
      const float ii = fmaf(2.f * a, bb, (float)ci[j]);
      nr[j] = rr; ni[j] = ii;
      ss = fmaf(rr, rr, ss);
      ss = fmaf(ii, ii, ss);
    }
#pragma unroll
    for (int off = 32; off; off >>= 1) ss += __shfl_xor(ss, off);
    const float nrm = sqrtf(ss + 1e-12f);
    const float sc  = 2.0f / fmaxf(nrm, 2.0f);
#pragma unroll
    for (int j = 0; j < 8; ++j) { zre[j] = nr[j] * sc; zim[j] = ni[j] * sc; }
    if (t >= t0) {
      bf16_t* yrow = y + ((size_t)b * S_DIM + t) * D_DIM;
      bf16x8 yr, yi;
#pragma unroll
      for (int j = 0; j < 8; ++j) { yr[j] = (bf16_t)zre[j]; yi[j] = (bf16_t)zim[j]; }
      ((bf16x8*)yrow)[lane]         = yr;
      ((bf16x8*)(yrow + 512))[lane] = yi;
    }
    cr = crn; ci = cin;
  }
}

extern "C" void kernel_launch(void* const* d_in, const int* in_sizes, int n_in,
                              void* d_out, int out_size, void* d_ws, size_t ws_size,
                              hipStream_t stream) {
  const float* x     = (const float*)d_in[0];
  const float* gamma = (const float*)d_in[1];
  const float* beta  = (const float*)d_in[2];
  const float* W_in  = (const float*)d_in[3];
  const float* b_in  = (const float*)d_in[4];
  const float* W_out = (const float*)d_in[5];
  const float* b_out = (const float*)d_in[6];
  float* out = (float*)d_out;

  char* ws = (char*)d_ws;
  bf16_t* hy  = (bf16_t*)(ws);                  // 32 MiB: h, later reused for y
  bf16_t* cbf = (bf16_t*)(ws + (32ull << 20));  // 32 MiB: c (bf16)
  bf16_t* wti = (bf16_t*)(ws + (64ull << 20));  // 2 MiB:  W_in^T bf16
  bf16_t* wto = (bf16_t*)(ws + (66ull << 20));  // 2 MiB:  W_out^T bf16

  transpose_kernel<<<dim3(32, 32), 256, 0, stream>>>(W_in, wti);
  transpose_kernel<<<dim3(32, 32), 256, 0, stream>>>(W_out, wto);
  ln_kernel<<<M_DIM, 64, 0, stream>>>(x, gamma, beta, hy);
  gemm_nt_kernel<0><<<256, 512, 0, stream>>>(hy, wti, b_in, nullptr, cbf);
  scan_kernel<<<dim3(S_DIM / CHUNK, B_DIM), 64, 0, stream>>>(cbf, hy);
  gemm_nt_kernel<1><<<256, 512, 0, stream>>>(hy, wto, b_out, x, out);
}

// Round 3
// 179.020 us; speedup vs baseline: 1.0933x; 1.0028x over previous
//
#include <hip/hip_runtime.h>

typedef __bf16 bf16_t;
typedef __bf16 bf16x8 __attribute__((ext_vector_type(8)));
typedef __bf16 bf16x4 __attribute__((ext_vector_type(4)));
typedef float  f32x4  __attribute__((ext_vector_type(4)));

#define B_DIM 4
#define S_DIM 4096
#define D_DIM 1024
#define M_DIM (B_DIM * S_DIM)   // 16384 rows

#define CHUNK 64   // scan output steps per block
#define WARM  24   // scan warm-up steps

__device__ __forceinline__ void g2l16(const void* g, void* l) {
  __builtin_amdgcn_global_load_lds(
      (const __attribute__((address_space(1))) void*)g,
      (__attribute__((address_space(3))) void*)l, 16, 0, 0);
}

// ---------------- LayerNorm fp32 -> bf16, one wave per row ----------------
__global__ __launch_bounds__(64) void ln_kernel(
    const float* __restrict__ x, const float* __restrict__ gamma,
    const float* __restrict__ beta, bf16_t* __restrict__ h) {
  const int row  = blockIdx.x;
  const int lane = threadIdx.x;
  const float4* xr = (const float4*)(x + (size_t)row * D_DIM);
  float4 v[4];
  float s = 0.f, s2 = 0.f;
#pragma unroll
  for (int j = 0; j < 4; ++j) {
    v[j] = xr[j * 64 + lane];
    s += v[j].x + v[j].y + v[j].z + v[j].w;
    s2 = fmaf(v[j].x, v[j].x, s2);
    s2 = fmaf(v[j].y, v[j].y, s2);
    s2 = fmaf(v[j].z, v[j].z, s2);
    s2 = fmaf(v[j].w, v[j].w, s2);
  }
#pragma unroll
  for (int off = 32; off; off >>= 1) {
    s  += __shfl_xor(s, off);
    s2 += __shfl_xor(s2, off);
  }
  const float mu  = s * (1.f / (float)D_DIM);
  const float var = fmaf(-mu, mu, s2 * (1.f / (float)D_DIM));
  const float inv = rsqrtf(var + 1e-5f);
  bf16_t* hr = h + (size_t)row * D_DIM;
#pragma unroll
  for (int j = 0; j < 4; ++j) {
    const float4 g4 = ((const float4*)gamma)[j * 64 + lane];
    const float4 b4 = ((const float4*)beta)[j * 64 + lane];
    bf16x4 o;
    o[0] = (bf16_t)fmaf((v[j].x - mu) * inv, g4.x, b4.x);
    o[1] = (bf16_t)fmaf((v[j].y - mu) * inv, g4.y, b4.y);
    o[2] = (bf16_t)fmaf((v[j].z - mu) * inv, g4.z, b4.z);
    o[3] = (bf16_t)fmaf((v[j].w - mu) * inv, g4.w, b4.w);
    ((bf16x4*)hr)[j * 64 + lane] = o;
  }
}

// ------------- W [K][N] fp32  ->  WT [N][K] bf16 (tiled transpose) --------
__global__ __launch_bounds__(256) void transpose_kernel(
    const float* __restrict__ W, bf16_t* __restrict__ WT) {
  __shared__ float tile[32][33];
  const int tx = threadIdx.x & 31;
  const int ty = threadIdx.x >> 5;
  const int bn = blockIdx.x * 32;
  const int bk = blockIdx.y * 32;
#pragma unroll
  for (int i = 0; i < 32; i += 8)
    tile[ty + i][tx] = W[(size_t)(bk + ty + i) * D_DIM + bn + tx];
  __syncthreads();
#pragma unroll
  for (int i = 0; i < 32; i += 8)
    WT[(size_t)(bn + ty + i) * D_DIM + bk + tx] = (bf16_t)tile[tx][ty + i];
}

// ================= bf16 NT GEMM, 256x256 tile, 8-phase schedule ===========
// C[M][N] = A[M][K] * BT[N][K]^T ; MODE 0: bf16(acc+bias); MODE 1: f32 +x
// K-tile = BK 64 = 2 kk-halves of 32. LDS buffer layout per dbuf (64KB):
//   A_k0 [256][32] @0, A_k1 @16K, B_k0 @32K, B_k1 @48K
// Within a [256][32] region (64B rows, 4 slots of 16B):
//   element (row, k) stored at slot (k>>3) ^ ((row>>1)&3)  [R2: 0 conflicts]
#define NT2 16   // K / 64

#define VMCNT(n) asm volatile("s_waitcnt vmcnt(" #n ")" ::: "memory")
#define BARRIER()                      \
  {                                    \
    asm volatile("" ::: "memory");     \
    __builtin_amdgcn_s_barrier();      \
    asm volatile("" ::: "memory");     \
  }
#define DSR(d, a, off) \
  asm volatile("ds_read_b128 %0, %1 offset:" #off : "=v"(d) : "v"(a))

template <int MODE>
__global__ __launch_bounds__(512, 2) void gemm_nt_kernel(
    const bf16_t* __restrict__ A, const bf16_t* __restrict__ BT,
    const float* __restrict__ bias, const float* __restrict__ xres,
    void* __restrict__ Cout) {
  __shared__ __attribute__((aligned(16))) char lds[2][65536];
  char* ldsc = (char*)lds;
  const int tid  = threadIdx.x;
  const int lane = tid & 63;
  const int wave = tid >> 6;           // 0..7
  const int wr = wave >> 2;            // 0..1 (M half)
  const int wc = wave & 3;             // 0..3 (N quarter)
  const int bid = blockIdx.x;
  const int swz = (bid & 7) * 32 + (bid >> 3);   // 256 blocks, 8 XCDs
  const int m0 = (swz >> 2) * 256;
  const int n0 = (swz & 3) * 256;

  // staging: thread covers (row = tid>>2, phys slot = tid&3); logical slot
  // s = (tid&3) ^ ((tid>>3)&3); source k-elems s*8..+8
  const int ke = (((tid & 3) ^ ((tid >> 3) & 3)) << 3);
  const bf16_t* srcA = A  + (size_t)(m0 + (tid >> 2)) * D_DIM + ke;
  const bf16_t* srcB = BT + (size_t)(n0 + (tid >> 2)) * D_DIM + ke;
  const int l16 = tid * 16;

  // fragment read bases (32-bit LDS addresses for asm ds_read)
  const uint32_t lbase = (uint32_t)(uintptr_t)&lds[0][0];
  const int sw = (((lane >> 4) ^ ((lane >> 1) & 3)) << 4);
  const uint32_t aRd = lbase + (uint32_t)((wr * 128 + (lane & 15)) * 64 + sw);
  const uint32_t bRd = lbase + 32768u +
                       (uint32_t)((wc * 64 + (lane & 15)) * 64 + sw);

  f32x4 acc[8][4];
#pragma unroll
  for (int m = 0; m < 8; ++m)
#pragma unroll
    for (int n = 0; n < 4; ++n) acc[m][n] = (f32x4){0.f, 0.f, 0.f, 0.f};

#define STGA(kt, bufb, kk)                                          \
  {                                                                 \
    const bf16_t* s_ = srcA + (size_t)(kt) * 64 + (kk) * 32;        \
    char* d_ = ldsc + (size_t)(bufb) * 65536 + (kk) * 16384 + l16;  \
    g2l16(s_, d_);                                                  \
    g2l16(s_ + 131072, d_ + 8192);                                  \
  }
#define STGB(kt, bufb, kk)                                          \
  {                                                                 \
    const bf16_t* s_ = srcB + (size_t)(kt) * 64 + (kk) * 32;        \
    char* d_ = ldsc + (size_t)(bufb) * 65536 + 32768 +              \
               (kk) * 16384 + l16;                                  \
    g2l16(s_, d_);                                                  \
    g2l16(s_ + 131072, d_ + 8192);                                  \
  }

#define MFMA16(MH)                                                          \
  _Pragma("unroll") for (int mm = 0; mm < 4; ++mm)                          \
      _Pragma("unroll") for (int nn = 0; nn < 4; ++nn)                      \
          acc[(MH) * 4 + mm][nn] = __builtin_amdgcn_mfma_f32_16x16x32_bf16( \
              af[mm], bfr[nn], acc[(MH) * 4 + mm][nn], 0, 0, 0);

// one phase: issue this phase's ds_reads, issue stage, sync, 16 MFMA
#define PHASE(KKOFF, MH, LOADB, STAGE_STMT, TAIL_STMT)              \
  {                                                                 \
    const uint32_t aA = aRd + bo + (KKOFF) + (MH) * 4096u;          \
    DSR(af[0], aA, 0);                                              \
    DSR(af[1], aA, 1024);                                           \
    DSR(af[2], aA, 2048);                                           \
    DSR(af[3], aA, 3072);                                           \
    if (LOADB) {                                                    \
      const uint32_t bA = bRd + bo + (KKOFF);                       \
      DSR(bfr[0], bA, 0);                                           \
      DSR(bfr[1], bA, 1024);                                        \
      DSR(bfr[2], bA, 2048);                                        \
      DSR(bfr[3], bA, 3072);                                        \
    }                                                               \
    STAGE_STMT;                                                     \
    BARRIER();                                                      \
    asm volatile("s_waitcnt lgkmcnt(0)" ::: "memory");              \
    __builtin_amdgcn_sched_barrier(0);                              \
    __builtin_amdgcn_s_setprio(1);                                  \
    MFMA16(MH);                                                     \
    __builtin_amdgcn_s_setprio(0);                                  \
    TAIL_STMT;                                                      \
    BARRIER();                                                      \
  }

  // prologue: tile0 (all 4 regions) + tile1 (kk0 regions); drain to 4
  STGA(0, 0, 0); STGB(0, 0, 0); STGA(0, 0, 1); STGB(0, 0, 1);
  STGA(1, 1, 0); STGB(1, 1, 0);
  VMCNT(4);
  BARRIER();

  for (int W = 0; W < NT2; ++W) {
    const uint32_t bo = (uint32_t)(W & 1) * 65536u;
    bf16x8 af[4], bfr[4];
    // s0: (kk0, mh0) + stage next tile's kk1 regions into other buf
    PHASE(0u, 0, true,
          { if (W < NT2 - 1) { STGA(W + 1, (W & 1) ^ 1, 1); STGB(W + 1, (W & 1) ^ 1, 1); } },
          {});
    // s1: (kk0, mh1)
    PHASE(0u, 1, false, {}, {});
    // s2: (kk1, mh0) + stage tile W+2's A_k0 into this buf
    PHASE(16384u, 0, true,
          { if (W < NT2 - 2) { STGA(W + 2, (W & 1), 0); } },
          {});
    // s3: (kk1, mh1) + stage tile W+2's B_k0; K-tile boundary vmcnt
    PHASE(16384u, 1, false,
          { if (W < NT2 - 2) { STGB(W + 2, (W & 1), 0); } },
          { if (W < NT2 - 2) { VMCNT(4); } else if (W == NT2 - 2) { VMCNT(0); } });
  }

#undef PHASE
#undef MFMA16
#undef STGA
#undef STGB

  // epilogue: C/D layout col = lane&15, row = (lane>>4)*4 + r
  const int rbase = m0 + wr * 128 + ((lane >> 4) << 2);
  const int cbase = n0 + wc * 64 + (lane & 15);
#pragma unroll
  for (int n = 0; n < 4; ++n) {
    const int col = cbase + n * 16;
    const float bn = bias[col];
#pragma unroll
    for (int m = 0; m < 8; ++m) {
      const int row = rbase + m * 16;
#pragma unroll
      for (int r = 0; r < 4; ++r) {
        const size_t idx = (size_t)(row + r) * D_DIM + col;
        if (MODE == 0)
          ((bf16_t*)Cout)[idx] = (bf16_t)(acc[m][n][r] + bn);
        else
          ((float*)Cout)[idx] = xres[idx] + acc[m][n][r] + bn;
      }
    }
  }
}

// ---------------- chunked chaotic scan, one wave per (batch, chunk) -------
__global__ __launch_bounds__(64) void scan_kernel(
    const bf16_t* __restrict__ c, bf16_t* __restrict__ y) {
  const int b     = blockIdx.y;
  const int chunk = blockIdx.x;
  const int t0    = chunk * CHUNK;
  const int start = (chunk == 0) ? 0 : t0 - WARM;
  const int tend  = t0 + CHUNK;
  const int lane  = threadIdx.x;

  float zre[8], zim[8];
#pragma unroll
  for (int j = 0; j < 8; ++j) { zre[j] = 0.f; zim[j] = 0.f; }

  const bf16_t* crow = c + ((size_t)b * S_DIM + start) * D_DIM;
  bf16x8 cr = ((const bf16x8*)crow)[lane];
  bf16x8 ci = ((const bf16x8*)(crow + 512))[lane];

  for (int t = start; t < tend; ++t) {
    bf16x8 crn = cr, cin = ci;
    if (t + 1 < tend) {
      const bf16_t* nrow = c + ((size_t)b * S_DIM + (t + 1)) * D_DIM;
      crn = ((const bf16x8*)nrow)[lane];
      cin = ((const bf16x8*)(nrow + 512))[lane];
    }
    float nr[8], ni[8];
    float ss = 0.f;
#pragma unroll
    for (int j = 0; j < 8; ++j) {
      const float a  = zre[j], bb = zim[j];
      const float rr = fmaf(a, a, fmaf(-bb, bb, (float)cr[j]));
      const float ii = fmaf(2.f * a, bb, (float)ci[j]);
      nr[j] = rr; ni[j] = ii;
      ss = fmaf(rr, rr, ss);
      ss = fmaf(ii, ii, ss);
    }
#pragma unroll
    for (int off = 32; off; off >>= 1) ss += __shfl_xor(ss, off);
    const float nrm = sqrtf(ss + 1e-12f);
    const float sc  = 2.0f / fmaxf(nrm, 2.0f);
#pragma unroll
    for (int j = 0; j < 8; ++j) { zre[j] = nr[j] * sc; zim[j] = ni[j] * sc; }
    if (t >= t0) {
      bf16_t* yrow = y + ((size_t)b * S_DIM + t) * D_DIM;
      bf16x8 yr, yi;
#pragma unroll
      for (int j = 0; j < 8; ++j) { yr[j] = (bf16_t)zre[j]; yi[j] = (bf16_t)zim[j]; }
      ((bf16x8*)yrow)[lane]         = yr;
      ((bf16x8*)(yrow + 512))[lane] = yi;
    }
    cr = crn; ci = cin;
  }
}

extern "C" void kernel_launch(void* const* d_in, const int* in_sizes, int n_in,
                              void* d_out, int out_size, void* d_ws, size_t ws_size,
                              hipStream_t stream) {
  const float* x     = (const float*)d_in[0];
  const float* gamma = (const float*)d_in[1];
  const float* beta  = (const float*)d_in[2];
  const float* W_in  = (const float*)d_in[3];
  const float* b_in  = (const float*)d_in[4];
  const float* W_out = (const float*)d_in[5];
  const float* b_out = (const float*)d_in[6];
  float* out = (float*)d_out;

  char* ws = (char*)d_ws;
  bf16_t* hy  = (bf16_t*)(ws);                  // 32 MiB: h, later reused for y
  bf16_t* cbf = (bf16_t*)(ws + (32ull << 20));  // 32 MiB: c (bf16)
  bf16_t* wti = (bf16_t*)(ws + (64ull << 20));  // 2 MiB:  W_in^T bf16
  bf16_t* wto = (bf16_t*)(ws + (66ull << 20));  // 2 MiB:  W_out^T bf16

  transpose_kernel<<<dim3(32, 32), 256, 0, stream>>>(W_in, wti);
  transpose_kernel<<<dim3(32, 32), 256, 0, stream>>>(W_out, wto);
  ln_kernel<<<M_DIM, 64, 0, stream>>>(x, gamma, beta, hy);
  gemm_nt_kernel<0><<<256, 512, 0, stream>>>(hy, wti, b_in, nullptr, cbf);
  scan_kernel<<<dim3(S_DIM / CHUNK, B_DIM), 64, 0, stream>>>(cbf, hy);
  gemm_nt_kernel<1><<<256, 512, 0, stream>>>(hy, wto, b_out, x, out);
}